// Round 19
// baseline (30.186 us; speedup 1.0000x reference)
//
#include <hip/hip_runtime.h>
#include <math.h>

#define EPSV 1e-6f
constexpr int N_ = 900, B_ = 8, C_ = 256, H_ = 8, D_ = 32;
constexpr int M_TOT = N_ * B_;        // 7200 rows
constexpr int BM  = 32;               // rows per block
constexpr int NBLK = M_TOT / BM;      // 225 blocks
constexpr int VS  = 272;              // q/k/v LDS row stride (shorts)
// fused LDS: W wave-private dbuf 8x8K | Aq 16K | Ak 16K | q/k/v bf16
constexpr int OFF_AQ = 65536;
constexpr int OFF_AK = 81920;
constexpr int OFF_Q  = 98304;
constexpr int OFF_K  = OFF_Q + BM * VS * 2;    // 115712
constexpr int OFF_V  = OFF_K + BM * VS * 2;    // 133120
constexpr int LDS1   = OFF_V + BM * VS * 2;    // 150528 bytes
constexpr int LDS2   = 131072 + 16384;         // outproj: 128K Wo + 16K As

typedef __attribute__((ext_vector_type(8))) short short8;       // 8 bf16
typedef __attribute__((ext_vector_type(4))) float f32x4;
typedef __attribute__((ext_vector_type(2))) float f32x2;
typedef __attribute__((ext_vector_type(2))) unsigned short us2;

__device__ __forceinline__ unsigned short f2bf(float f) {   // RNE fp32->bf16
    unsigned int u = __float_as_uint(f);
    return (unsigned short)((u + 0x7FFFu + ((u >> 16) & 1u)) >> 16);
}
__device__ __forceinline__ float bf2f(unsigned short u) {
    return __uint_as_float(((unsigned int)u) << 16);
}
// swizzled byte offset in a [rows]x256-bf16 LDS tile (row stride 512B)
__device__ __forceinline__ int swz(int row, int kElem) {
    int b = (row << 9) + (kElem << 1);
    return b ^ ((row & 7) << 4);
}

// ---- DPP 16-lane sum: VALU-latency, same lane combos as shfl_xor 1/2/4/8 ----
template<int CTRL>
__device__ __forceinline__ float dpp_add(float v) {
    int x = __builtin_amdgcn_update_dpp(0, __float_as_int(v), CTRL, 0xF, 0xF, true);
    return v + __int_as_float(x);
}
__device__ __forceinline__ float red16(float v) {
    v = dpp_add<0xB1>(v);    // quad_perm [1,0,3,2]
    v = dpp_add<0x4E>(v);    // quad_perm [2,3,0,1]
    v = dpp_add<0x124>(v);   // row_ror:4
    v = dpp_add<0x128>(v);   // row_ror:8
    return v;
}

// ---------------------------------------------------------------------------
// prep: pack Wq|Wk|Wv|Wo (fp32 row-major 256x256) -> bf16, concatenated.
// ---------------------------------------------------------------------------
__global__ __launch_bounds__(256)
void pack_w(const float* __restrict__ Wq, const float* __restrict__ Wk,
            const float* __restrict__ Wv, const float* __restrict__ Wo,
            unsigned short* __restrict__ wbf)
{
    const int i = (blockIdx.x * 256 + threadIdx.x) * 8;
    const float* src = (i < 65536) ? Wq : (i < 131072) ? Wk
                     : (i < 196608) ? Wv : Wo;
    const int off = i & 65535;
    const float4 a = *reinterpret_cast<const float4*>(src + off);
    const float4 b = *reinterpret_cast<const float4*>(src + off + 4);
    short8 p;
    p[0]=(short)f2bf(a.x); p[1]=(short)f2bf(a.y);
    p[2]=(short)f2bf(a.z); p[3]=(short)f2bf(a.w);
    p[4]=(short)f2bf(b.x); p[5]=(short)f2bf(b.y);
    p[6]=(short)f2bf(b.z); p[7]=(short)f2bf(b.w);
    *reinterpret_cast<short8*>(wbf + i) = p;
}

// ---------------------------------------------------------------------------
// WAVE-PRIVATE async-DMA stage of this wave's 32-col x 64-k W slice (4 KB).
// ---------------------------------------------------------------------------
__device__ __forceinline__ void stageW32(const unsigned short* Wmat, int kkElem,
                                         char* wbufLds, int cw, int lane)
{
    #pragma unroll
    for (int n = 0; n < 4; ++n) {
        const int L  = n * 1024 + lane * 16;              // 0..4095 local byte
        const int cl = L >> 7;                            // local col 0..31
        const int kb = (L & 127) ^ ((cl & 7) << 4);       // inverse swizzle
        const char* src = (const char*)Wmat + (size_t)(cw + cl) * 512
                        + kkElem * 2 + kb;
        __builtin_amdgcn_global_load_lds(
            (const __attribute__((address_space(1))) unsigned int*)src,
            (__attribute__((address_space(3))) unsigned int*)(wbufLds + n * 1024),
            16, 0, 0);
    }
}

// one step: 4 A ds_reads + 4 swizzled W ds_reads + 8 MFMA (wave-local W buf)
__device__ __forceinline__ void step_mm32(const unsigned char* At, const char* wb,
                                          int kkA, int lrow, int kg8,
                                          f32x4 acc[2][2])
{
    #pragma unroll
    for (int kh = 0; kh < 2; ++kh) {
        const short8 a0 = *reinterpret_cast<const short8*>(At + swz(lrow,      kkA + kh*32 + kg8));
        const short8 a1 = *reinterpret_cast<const short8*>(At + swz(16 + lrow, kkA + kh*32 + kg8));
        #pragma unroll
        for (int j = 0; j < 2; ++j) {
            const int cl = j*16 + lrow;                   // local col 0..31
            const short8 bfr = *reinterpret_cast<const short8*>(
                wb + cl*128 + ((kh*64 + kg8*2) ^ ((cl & 7) << 4)));
            acc[0][j] = __builtin_amdgcn_mfma_f32_16x16x32_bf16(a0, bfr, acc[0][j], 0, 0, 0);
            acc[1][j] = __builtin_amdgcn_mfma_f32_16x16x32_bf16(a1, bfr, acc[1][j], 0, 0, 0);
        }
    }
}

// ---------------------------------------------------------------------------
// Kernel 1: fused q/k/v projections + attention. 512 threads = 8 waves,
// each wave owns 32 output cols; 12-step K-loop, wave-private dbuf,
// counted vmcnt(4), no in-loop barriers. pos read directly in epilogues.
// attn out -> bf16 flat (B,H,N,D).   (unchanged from round 18)
// ---------------------------------------------------------------------------
__global__ __launch_bounds__(512)
void fused_qkva(const float* __restrict__ query, const float* __restrict__ key,
                const float* __restrict__ qpos,  const float* __restrict__ kpos,
                const unsigned short* __restrict__ wbf,
                const float* __restrict__ bq, const float* __restrict__ bk,
                const float* __restrict__ bv,
                unsigned short* __restrict__ abf)
{
    extern __shared__ char smem[];
    char* Wb = smem;                                      // 8 x (2 x 4 KB)
    unsigned char* Aq = (unsigned char*)(smem + OFF_AQ);  // 16 KB
    unsigned char* Ak = (unsigned char*)(smem + OFF_AK);  // 16 KB
    unsigned short* q_sb = (unsigned short*)(smem + OFF_Q);   // [32][272] bf16
    unsigned short* k_sb = (unsigned short*)(smem + OFF_K);
    unsigned short* v_sb = (unsigned short*)(smem + OFF_V);

    const int tid = threadIdx.x;
    const int r0  = blockIdx.x * BM;
    const int wave = tid >> 6, lane = tid & 63;
    const int cw = wave * 32;                             // wave's 32 cols
    char* mywb = Wb + wave * 8192;                        // wave-private dbuf

    // ---- prologue: DMA slice 0 of Wq, then register-stage A tiles ----
    stageW32(wbf, 0, mywb, cw, lane);

    {
        const int trow = tid >> 5, k0 = (tid & 31) * 8;   // trow 0..15
        #pragma unroll
        for (int i = 0; i < 2; ++i) {
            const int row = trow + i * 16;
            const float* xr = query + (size_t)(r0 + row) * C_ + k0;
            const float* kr = key   + (size_t)(r0 + row) * C_ + k0;
            const float4 a0 = *reinterpret_cast<const float4*>(xr);
            const float4 a1 = *reinterpret_cast<const float4*>(xr + 4);
            const float4 b0 = *reinterpret_cast<const float4*>(kr);
            const float4 b1 = *reinterpret_cast<const float4*>(kr + 4);
            short8 pa;
            pa[0]=(short)f2bf(a0.x); pa[1]=(short)f2bf(a0.y);
            pa[2]=(short)f2bf(a0.z); pa[3]=(short)f2bf(a0.w);
            pa[4]=(short)f2bf(a1.x); pa[5]=(short)f2bf(a1.y);
            pa[6]=(short)f2bf(a1.z); pa[7]=(short)f2bf(a1.w);
            *reinterpret_cast<short8*>(Aq + swz(row, k0)) = pa;
            short8 pb;
            pb[0]=(short)f2bf(b0.x); pb[1]=(short)f2bf(b0.y);
            pb[2]=(short)f2bf(b0.z); pb[3]=(short)f2bf(b0.w);
            pb[4]=(short)f2bf(b1.x); pb[5]=(short)f2bf(b1.y);
            pb[6]=(short)f2bf(b1.z); pb[7]=(short)f2bf(b1.w);
            *reinterpret_cast<short8*>(Ak + swz(row, k0)) = pb;
        }
    }

    const int lrow = lane & 15, kg8 = (lane >> 4) * 8;
    const int crow0 = (lane >> 4) * 4, ccol = lane & 15;

    // ---- prefetch biases only (pos deferred to epilogues) ----
    float bqv[2], bkv[2], bvv[2];
    #pragma unroll
    for (int j = 0; j < 2; ++j) {
        const int ch = cw + j*16 + ccol;
        bqv[j] = bq[ch]; bkv[j] = bk[ch]; bvv[j] = bv[ch];
    }

    __syncthreads();   // drains slice-0 DMA + A ds_writes

    // ---- 12-step pipelined K-loop, barrier-free (wave self-paced) ----
    f32x4 qacc[2][2] = {}; f32x4 kacc[2][2] = {}; f32x4 vacc[2][2] = {};

    #pragma unroll
    for (int st = 0; st < 12; ++st) {
        if (st < 11) {
            const int nx = st + 1;
            stageW32(wbf + (nx >> 2) * 65536, (nx & 3) * 64,
                     mywb + (nx & 1) * 4096, cw, lane);
            asm volatile("s_waitcnt vmcnt(4)" ::: "memory");
        } else {
            asm volatile("s_waitcnt vmcnt(0)" ::: "memory");
        }

        const char* wb = mywb + (st & 1) * 4096;
        const int kkA = (st & 3) * 64;
        if (st < 4)      step_mm32(Aq, wb, kkA, lrow, kg8, qacc);
        else if (st < 8) step_mm32(Ak, wb, kkA, lrow, kg8, kacc);
        else             step_mm32(Ak, wb, kkA, lrow, kg8, vacc);

        if (st == 3) {   // q epilogue -> q_sb (bf16, sigmoid), pos read direct
            #pragma unroll
            for (int j = 0; j < 2; ++j) {
                const int ch = cw + j*16 + ccol;
                #pragma unroll
                for (int rh = 0; rh < 2; ++rh)
                    #pragma unroll
                    for (int r_ = 0; r_ < 4; ++r_) {
                        const int gr = r0 + rh*16 + crow0 + r_;
                        float v = qacc[rh][j][r_] + bqv[j]
                                + qpos[(size_t)gr * C_ + ch];
                        q_sb[(rh*16+crow0+r_)*VS + ch] = f2bf(1.f/(1.f+__expf(-v)));
                    }
            }
        }
        if (st == 7) {   // k epilogue, pos read direct
            #pragma unroll
            for (int j = 0; j < 2; ++j) {
                const int ch = cw + j*16 + ccol;
                #pragma unroll
                for (int rh = 0; rh < 2; ++rh)
                    #pragma unroll
                    for (int r_ = 0; r_ < 4; ++r_) {
                        const int gr = r0 + rh*16 + crow0 + r_;
                        float v = kacc[rh][j][r_] + bkv[j]
                                + kpos[(size_t)gr * C_ + ch];
                        k_sb[(rh*16+crow0+r_)*VS + ch] = f2bf(1.f/(1.f+__expf(-v)));
                    }
            }
        }
        if (st == 11) {  // v epilogue (no pos, no sigmoid)
            #pragma unroll
            for (int j = 0; j < 2; ++j) {
                const int ch = cw + j*16 + ccol;
                #pragma unroll
                for (int rh = 0; rh < 2; ++rh)
                    #pragma unroll
                    for (int r_ = 0; r_ < 4; ++r_)
                        v_sb[(rh*16+crow0+r_)*VS + ch] =
                            f2bf(vacc[rh][j][r_] + bvv[j]);
            }
        }
    }

    __syncthreads();   // qkv LDS complete

    // ---- attention: 16 threads/location, 32 locations (512 threads) ----
    {
        const int loc = tid >> 4, tt = tid & 15, d0 = tt * 2;
        const int gr = r0 + loc;                 // global row in (n,b) order
        const int nn = gr >> 3, bb = gr & 7;
        const unsigned short* qr = q_sb + loc * VS + d0;
        const unsigned short* kr = k_sb + loc * VS + d0;
        const unsigned short* vr = v_sb + loc * VS + d0;
        f32x2 qh[8], kh[8], vh[8];
        #pragma unroll
        for (int h = 0; h < 8; ++h) {
            const us2 tq = *reinterpret_cast<const us2*>(qr + (h << 5));
            const us2 tk = *reinterpret_cast<const us2*>(kr + (h << 5));
            const us2 tv = *reinterpret_cast<const us2*>(vr + (h << 5));
            qh[h][0] = bf2f(tq[0]); qh[h][1] = bf2f(tq[1]);
            kh[h][0] = bf2f(tk[0]); kh[h][1] = bf2f(tk[1]);
            vh[h][0] = bf2f(tv[0]); vh[h][1] = bf2f(tv[1]);
        }

        // ---- pass 1: p1/p2 partials, then batched reduce
        float pr[8], ps[8];
        {
            f32x2 ck = {0,0}, cq = {0,0};
            #pragma unroll
            for (int h = 0; h < 8; ++h) {
                float p1 = 0.f, p2 = 0.f;
                #pragma unroll
                for (int j = 0; j < 2; ++j) {
                    ck[j] += kh[h][j]; cq[j] += qh[h][j];
                    p1 += (qh[h][j] + EPSV) * (ck[j] + EPSV);
                    p2 += (kh[h][j] + EPSV) * (cq[j] + EPSV);
                }
                pr[h] = p1; ps[h] = p2;
            }
        }
        #pragma unroll
        for (int h = 0; h < 8; ++h) pr[h] = red16(pr[h]);
        #pragma unroll
        for (int h = 0; h < 8; ++h) ps[h] = red16(ps[h]);

        float ir1[8], so_[8];
        #pragma unroll
        for (int h = 0; h < 8; ++h) {
            ir1[h] = 1.f / pr[h];
            so_[h] = (float)(h+1) / ps[h];
        }

        // ---- pass 2: p3/p4 partials, then batched reduce
        float pt[8], pu[8];
        {
            f32x2 c2 = {0,0}, c3 = {0,0};
            #pragma unroll
            for (int h = 0; h < 8; ++h) {
                const float sih = (float)(h+1) * ir1[h];
                float p3 = 0.f, p4 = 0.f;
                #pragma unroll
                for (int j = 0; j < 2; ++j) {
                    c2[j] += kh[h][j] * so_[h];
                    c3[j] += qh[h][j] * sih;
                    p3 += (qh[h][j] + EPSV) * (c2[j] + EPSV);
                    p4 += (kh[h][j] + EPSV) * (c3[j] + EPSV);
                }
                pt[h] = p3; pu[h] = p4;
            }
        }
        #pragma unroll
        for (int h = 0; h < 8; ++h) pt[h] = red16(pt[h]);
        #pragma unroll
        for (int h = 0; h < 8; ++h) pu[h] = red16(pu[h]);

        float salloc[8], scomp[8];
        {
            float css = 0.f;
            #pragma unroll
            for (int h = 0; h < 8; ++h) {
                const float inv_n = 1.f / (float)(h+1);
                salloc[h] = 1.f / (1.f + __expf(-pt[h] * inv_n));
                const float consrc = fminf(1.f, fmaxf(-1.f, pu[h] * inv_n));
                const float cs = __expf(consrc);
                css += cs;
                scomp[h] = cs / css * (float)(h+1);
            }
        }

        // ---- pass 3 (qkv)
        #pragma unroll
        for (int h = 0; h < 8; ++h) {
            f32x2 qs2, a2 = {0,0};
            #pragma unroll
            for (int j = 0; j < 2; ++j) qs2[j] = qh[h][j] * ir1[h];
            #pragma unroll
            for (int h2 = 0; h2 <= h; ++h2) {
                float p = 0.f;
                #pragma unroll
                for (int j = 0; j < 2; ++j) p += qs2[j] * kh[h2][j];
                p = red16(p);
                const float w = p * scomp[h2];
                #pragma unroll
                for (int j = 0; j < 2; ++j) a2[j] += w * vh[h2][j];
            }
            us2 o;
            o[0] = f2bf(a2[0] * salloc[h]);
            o[1] = f2bf(a2[1] * salloc[h]);
            *reinterpret_cast<us2*>(abf + (size_t)bb*(H_*N_*D_) + (size_t)h*(N_*D_)
                                        + (size_t)nn*D_ + d0) = o;
        }
    }
}

// ---------------------------------------------------------------------------
// Kernel 2: out-projection + residual, DEEP-PREFETCH version.
// 512 threads = 8 waves x 32 cols. Per wave: issue As chunk (2 DMA loads,
// pre-swizzled source) then the ENTIRE Wo wave-slice (4 sub-slices = 16 DMA
// loads, 16 KB). vmcnt(16)+raw barrier gates the A tile only; the 4 compute
// steps use counted drains vmcnt(12/8/4/0) so 3 slices stay in flight.
// Bias/residual read directly in the epilogue.
// ---------------------------------------------------------------------------
__global__ __launch_bounds__(512)
void outproj(const unsigned short* __restrict__ abf,
             const unsigned short* __restrict__ wbf,
             const float* __restrict__ bo,
             const float* __restrict__ query,
             float* __restrict__ out)
{
    extern __shared__ char smem[];
    char* Wb = smem;                                     // 8 waves x 16 KB
    unsigned char* As = (unsigned char*)(smem + 131072); // 16 KB
    const int tid = threadIdx.x;
    const int r0  = blockIdx.x * BM;
    const int wave = tid >> 6, lane = tid & 63;
    const int cw = wave * 32;
    char* mywb = Wb + wave * 16384;                      // full Wo wave-slice
    const unsigned short* Wo = wbf + 3*65536;

    // ---- issue As stage via global_load_lds: wave w -> rows 4w..4w+3 ----
    // LDS linear byte (within As) = wave*2048 + n*1024 + lane*16; row = L>>9;
    // source = abf row start + ((L&511) ^ ((row&7)<<4))  [pre-swizzled]
    #pragma unroll
    for (int n = 0; n < 2; ++n) {
        const int Lb  = n * 1024 + lane * 16;            // 0..2047
        const int row = wave * 4 + (Lb >> 9);            // 0..31
        const int gr  = r0 + row;
        const int nn  = gr >> 3, bb = gr & 7;
        const char* src = (const char*)(abf + (size_t)bb * (N_*C_)
                                            + (size_t)nn * C_)
                        + ((Lb & 511) ^ ((row & 7) << 4));
        __builtin_amdgcn_global_load_lds(
            (const __attribute__((address_space(1))) unsigned int*)src,
            (__attribute__((address_space(3))) unsigned int*)(As + wave*2048 + n*1024),
            16, 0, 0);
    }

    // ---- issue FULL Wo wave-slice: 4 sub-slices x 4 loads = 16 DMA ----
    #pragma unroll
    for (int s = 0; s < 4; ++s)
        stageW32(Wo, s * 64, mywb + s * 4096, cw, lane);

    const int lrow = lane & 15, kg8 = (lane >> 4) * 8;
    const int crow0 = (lane >> 4) * 4, ccol = lane & 15;

    asm volatile("s_waitcnt vmcnt(16)" ::: "memory");   // As (2 oldest) done
    __builtin_amdgcn_s_barrier();                        // A tile visible
    __builtin_amdgcn_sched_barrier(0);

    f32x4 acc[2][2] = {};
    #pragma unroll
    for (int sp = 0; sp < 4; ++sp) {
        if (sp == 0)      asm volatile("s_waitcnt vmcnt(12)" ::: "memory");
        else if (sp == 1) asm volatile("s_waitcnt vmcnt(8)"  ::: "memory");
        else if (sp == 2) asm volatile("s_waitcnt vmcnt(4)"  ::: "memory");
        else              asm volatile("s_waitcnt vmcnt(0)"  ::: "memory");
        step_mm32(As, mywb + sp * 4096, sp * 64, lrow, kg8, acc);
    }

    // ---- epilogue: direct bias + residual reads ----
    #pragma unroll
    for (int j = 0; j < 2; ++j) {
        const int ch = cw + j*16 + ccol;
        const float bov = bo[ch];
        #pragma unroll
        for (int rh = 0; rh < 2; ++rh)
            #pragma unroll
            for (int r_ = 0; r_ < 4; ++r_) {
                const size_t g = (size_t)(r0 + rh*16 + crow0 + r_) * C_ + ch;
                out[g] = acc[rh][j][r_] + bov + query[g];
            }
    }
}

// ---------------------------------------------------------------------------
extern "C" void kernel_launch(void* const* d_in, const int* in_sizes, int n_in,
                              void* d_out, int out_size, void* d_ws, size_t ws_size,
                              hipStream_t stream)
{
    const float* query = (const float*)d_in[0];
    const float* key   = (const float*)d_in[1];
    const float* qpos  = (const float*)d_in[2];
    const float* kpos  = (const float*)d_in[3];
    const float* Wq = (const float*)d_in[4];  const float* bq = (const float*)d_in[5];
    const float* Wk = (const float*)d_in[6];  const float* bk = (const float*)d_in[7];
    const float* Wv = (const float*)d_in[8];  const float* bv = (const float*)d_in[9];
    const float* Wo = (const float*)d_in[10]; const float* bo = (const float*)d_in[11];

    unsigned short* wbf = (unsigned short*)d_ws;        // 4*65536 bf16 = 512 KB
    unsigned short* abf = wbf + 4*65536;                // B*N*C bf16 = 3.7 MB
    float* out = (float*)d_out;

    pack_w<<<128, 256, 0, stream>>>(Wq, Wk, Wv, Wo, wbf);
    fused_qkva<<<NBLK, 512, LDS1, stream>>>(query, key, qpos, kpos, wbf,
                                            bq, bk, bv, abf);
    outproj<<<NBLK, 512, LDS2, stream>>>(abf, wbf, bo, query, out);
}

// Round 20
// 29.676 us; speedup vs baseline: 1.0172x; 1.0172x over previous
//
#include <hip/hip_runtime.h>
#include <math.h>

#define EPSV 1e-6f
constexpr int N_ = 900, B_ = 8, C_ = 256, H_ = 8, D_ = 32;
constexpr int M_TOT = N_ * B_;        // 7200 rows
constexpr int BM  = 32;               // rows per block
constexpr int NBLK = M_TOT / BM;      // 225 blocks
constexpr int VS  = 272;              // q/k/v LDS row stride (shorts)
// fused LDS: W wave-private dbuf 8x8K | Aq 16K | Ak 16K | q/k/v bf16
constexpr int OFF_AQ = 65536;
constexpr int OFF_AK = 81920;
constexpr int OFF_Q  = 98304;
constexpr int OFF_K  = OFF_Q + BM * VS * 2;    // 115712
constexpr int OFF_V  = OFF_K + BM * VS * 2;    // 133120
constexpr int LDS1   = OFF_V + BM * VS * 2;    // 150528 bytes
constexpr int LDS2   = 81920;                  // outproj: 64K W + 16K As

typedef __attribute__((ext_vector_type(8))) short short8;       // 8 bf16
typedef __attribute__((ext_vector_type(4))) float f32x4;
typedef __attribute__((ext_vector_type(2))) float f32x2;
typedef __attribute__((ext_vector_type(2))) unsigned short us2;

__device__ __forceinline__ unsigned short f2bf(float f) {   // RNE fp32->bf16
    unsigned int u = __float_as_uint(f);
    return (unsigned short)((u + 0x7FFFu + ((u >> 16) & 1u)) >> 16);
}
__device__ __forceinline__ float bf2f(unsigned short u) {
    return __uint_as_float(((unsigned int)u) << 16);
}
// swizzled byte offset in a [rows]x256-bf16 LDS tile (row stride 512B)
__device__ __forceinline__ int swz(int row, int kElem) {
    int b = (row << 9) + (kElem << 1);
    return b ^ ((row & 7) << 4);
}

// ---- DPP 16-lane sum: VALU-latency, same lane combos as shfl_xor 1/2/4/8 ----
template<int CTRL>
__device__ __forceinline__ float dpp_add(float v) {
    int x = __builtin_amdgcn_update_dpp(0, __float_as_int(v), CTRL, 0xF, 0xF, true);
    return v + __int_as_float(x);
}
__device__ __forceinline__ float red16(float v) {
    v = dpp_add<0xB1>(v);    // quad_perm [1,0,3,2]
    v = dpp_add<0x4E>(v);    // quad_perm [2,3,0,1]
    v = dpp_add<0x124>(v);   // row_ror:4
    v = dpp_add<0x128>(v);   // row_ror:8
    return v;
}

// ---------------------------------------------------------------------------
// prep: pack Wq|Wk|Wv|Wo (fp32 row-major 256x256) -> bf16, concatenated.
// ---------------------------------------------------------------------------
__global__ __launch_bounds__(256)
void pack_w(const float* __restrict__ Wq, const float* __restrict__ Wk,
            const float* __restrict__ Wv, const float* __restrict__ Wo,
            unsigned short* __restrict__ wbf)
{
    const int i = (blockIdx.x * 256 + threadIdx.x) * 8;
    const float* src = (i < 65536) ? Wq : (i < 131072) ? Wk
                     : (i < 196608) ? Wv : Wo;
    const int off = i & 65535;
    const float4 a = *reinterpret_cast<const float4*>(src + off);
    const float4 b = *reinterpret_cast<const float4*>(src + off + 4);
    short8 p;
    p[0]=(short)f2bf(a.x); p[1]=(short)f2bf(a.y);
    p[2]=(short)f2bf(a.z); p[3]=(short)f2bf(a.w);
    p[4]=(short)f2bf(b.x); p[5]=(short)f2bf(b.y);
    p[6]=(short)f2bf(b.z); p[7]=(short)f2bf(b.w);
    *reinterpret_cast<short8*>(wbf + i) = p;
}

// ---------------------------------------------------------------------------
// WAVE-PRIVATE async-DMA stage of this wave's 32-col x 64-k W slice (4 KB).
// ---------------------------------------------------------------------------
__device__ __forceinline__ void stageW32(const unsigned short* Wmat, int kkElem,
                                         char* wbufLds, int cw, int lane)
{
    #pragma unroll
    for (int n = 0; n < 4; ++n) {
        const int L  = n * 1024 + lane * 16;              // 0..4095 local byte
        const int cl = L >> 7;                            // local col 0..31
        const int kb = (L & 127) ^ ((cl & 7) << 4);       // inverse swizzle
        const char* src = (const char*)Wmat + (size_t)(cw + cl) * 512
                        + kkElem * 2 + kb;
        __builtin_amdgcn_global_load_lds(
            (const __attribute__((address_space(1))) unsigned int*)src,
            (__attribute__((address_space(3))) unsigned int*)(wbufLds + n * 1024),
            16, 0, 0);
    }
}

// one step: 4 A ds_reads + 4 swizzled W ds_reads + 8 MFMA (wave-local W buf).
// MFMA cluster wrapped in s_setprio(1)/(0) — waves are self-paced (no
// barriers), so the CU scheduler can prefer the MFMA-entering wave (T5).
__device__ __forceinline__ void step_mm32(const unsigned char* At, const char* wb,
                                          int kkA, int lrow, int kg8,
                                          f32x4 acc[2][2])
{
    short8 a0[2], a1[2], bfr[2][2];
    #pragma unroll
    for (int kh = 0; kh < 2; ++kh) {
        a0[kh] = *reinterpret_cast<const short8*>(At + swz(lrow,      kkA + kh*32 + kg8));
        a1[kh] = *reinterpret_cast<const short8*>(At + swz(16 + lrow, kkA + kh*32 + kg8));
        #pragma unroll
        for (int j = 0; j < 2; ++j) {
            const int cl = j*16 + lrow;                   // local col 0..31
            bfr[kh][j] = *reinterpret_cast<const short8*>(
                wb + cl*128 + ((kh*64 + kg8*2) ^ ((cl & 7) << 4)));
        }
    }
    __builtin_amdgcn_s_setprio(1);
    #pragma unroll
    for (int kh = 0; kh < 2; ++kh)
        #pragma unroll
        for (int j = 0; j < 2; ++j) {
            acc[0][j] = __builtin_amdgcn_mfma_f32_16x16x32_bf16(a0[kh], bfr[kh][j], acc[0][j], 0, 0, 0);
            acc[1][j] = __builtin_amdgcn_mfma_f32_16x16x32_bf16(a1[kh], bfr[kh][j], acc[1][j], 0, 0, 0);
        }
    __builtin_amdgcn_s_setprio(0);
}

// ---------------------------------------------------------------------------
// Kernel 1: fused q/k/v projections + attention. 512 threads = 8 waves,
// each wave owns 32 output cols; 12-step K-loop, wave-private dbuf,
// counted vmcnt(4), no in-loop barriers. attn out -> bf16 flat (B,H,N,D).
// ---------------------------------------------------------------------------
__global__ __launch_bounds__(512)
void fused_qkva(const float* __restrict__ query, const float* __restrict__ key,
                const float* __restrict__ qpos,  const float* __restrict__ kpos,
                const unsigned short* __restrict__ wbf,
                const float* __restrict__ bq, const float* __restrict__ bk,
                const float* __restrict__ bv,
                unsigned short* __restrict__ abf)
{
    extern __shared__ char smem[];
    char* Wb = smem;                                      // 8 x (2 x 4 KB)
    unsigned char* Aq = (unsigned char*)(smem + OFF_AQ);  // 16 KB
    unsigned char* Ak = (unsigned char*)(smem + OFF_AK);  // 16 KB
    unsigned short* q_sb = (unsigned short*)(smem + OFF_Q);   // [32][272] bf16
    unsigned short* k_sb = (unsigned short*)(smem + OFF_K);
    unsigned short* v_sb = (unsigned short*)(smem + OFF_V);

    const int tid = threadIdx.x;
    const int r0  = blockIdx.x * BM;
    const int wave = tid >> 6, lane = tid & 63;
    const int cw = wave * 32;                             // wave's 32 cols
    char* mywb = Wb + wave * 8192;                        // wave-private dbuf

    // ---- prologue: DMA slice 0 of Wq, then register-stage A tiles ----
    stageW32(wbf, 0, mywb, cw, lane);

    {
        const int trow = tid >> 5, k0 = (tid & 31) * 8;   // trow 0..15
        #pragma unroll
        for (int i = 0; i < 2; ++i) {
            const int row = trow + i * 16;
            const float* xr = query + (size_t)(r0 + row) * C_ + k0;
            const float* kr = key   + (size_t)(r0 + row) * C_ + k0;
            const float4 a0 = *reinterpret_cast<const float4*>(xr);
            const float4 a1 = *reinterpret_cast<const float4*>(xr + 4);
            const float4 b0 = *reinterpret_cast<const float4*>(kr);
            const float4 b1 = *reinterpret_cast<const float4*>(kr + 4);
            short8 pa;
            pa[0]=(short)f2bf(a0.x); pa[1]=(short)f2bf(a0.y);
            pa[2]=(short)f2bf(a0.z); pa[3]=(short)f2bf(a0.w);
            pa[4]=(short)f2bf(a1.x); pa[5]=(short)f2bf(a1.y);
            pa[6]=(short)f2bf(a1.z); pa[7]=(short)f2bf(a1.w);
            *reinterpret_cast<short8*>(Aq + swz(row, k0)) = pa;
            short8 pb;
            pb[0]=(short)f2bf(b0.x); pb[1]=(short)f2bf(b0.y);
            pb[2]=(short)f2bf(b0.z); pb[3]=(short)f2bf(b0.w);
            pb[4]=(short)f2bf(b1.x); pb[5]=(short)f2bf(b1.y);
            pb[6]=(short)f2bf(b1.z); pb[7]=(short)f2bf(b1.w);
            *reinterpret_cast<short8*>(Ak + swz(row, k0)) = pb;
        }
    }

    const int lrow = lane & 15, kg8 = (lane >> 4) * 8;
    const int crow0 = (lane >> 4) * 4, ccol = lane & 15;

    // ---- prefetch pos + biases (retire during prologue drain) ----
    float qp[16], kp[16], bqv[2], bkv[2], bvv[2];
    #pragma unroll
    for (int j = 0; j < 2; ++j) {
        const int ch = cw + j*16 + ccol;
        bqv[j] = bq[ch]; bkv[j] = bk[ch]; bvv[j] = bv[ch];
        #pragma unroll
        for (int rh = 0; rh < 2; ++rh)
            #pragma unroll
            for (int r_ = 0; r_ < 4; ++r_) {
                const int gr = r0 + rh*16 + crow0 + r_;
                qp[j*8+rh*4+r_] = qpos[(size_t)gr * C_ + ch];
                kp[j*8+rh*4+r_] = kpos[(size_t)gr * C_ + ch];
            }
    }

    __syncthreads();   // drains slice-0 DMA + A ds_writes + prefetch loads

    // ---- 12-step pipelined K-loop, barrier-free (wave self-paced) ----
    f32x4 qacc[2][2] = {}; f32x4 kacc[2][2] = {}; f32x4 vacc[2][2] = {};

    #pragma unroll
    for (int st = 0; st < 12; ++st) {
        if (st < 11) {
            const int nx = st + 1;
            stageW32(wbf + (nx >> 2) * 65536, (nx & 3) * 64,
                     mywb + (nx & 1) * 4096, cw, lane);
            asm volatile("s_waitcnt vmcnt(4)" ::: "memory");
        } else {
            asm volatile("s_waitcnt vmcnt(0)" ::: "memory");
        }

        const char* wb = mywb + (st & 1) * 4096;
        const int kkA = (st & 3) * 64;
        if (st < 4)      step_mm32(Aq, wb, kkA, lrow, kg8, qacc);
        else if (st < 8) step_mm32(Ak, wb, kkA, lrow, kg8, kacc);
        else             step_mm32(Ak, wb, kkA, lrow, kg8, vacc);

        if (st == 3) {   // q epilogue -> q_sb (bf16, sigmoid)
            #pragma unroll
            for (int j = 0; j < 2; ++j) {
                const int ch = cw + j*16 + ccol;
                #pragma unroll
                for (int rh = 0; rh < 2; ++rh)
                    #pragma unroll
                    for (int r_ = 0; r_ < 4; ++r_) {
                        float v = qacc[rh][j][r_] + bqv[j] + qp[j*8+rh*4+r_];
                        q_sb[(rh*16+crow0+r_)*VS + ch] = f2bf(1.f/(1.f+__expf(-v)));
                    }
            }
        }
        if (st == 7) {   // k epilogue
            #pragma unroll
            for (int j = 0; j < 2; ++j) {
                const int ch = cw + j*16 + ccol;
                #pragma unroll
                for (int rh = 0; rh < 2; ++rh)
                    #pragma unroll
                    for (int r_ = 0; r_ < 4; ++r_) {
                        float v = kacc[rh][j][r_] + bkv[j] + kp[j*8+rh*4+r_];
                        k_sb[(rh*16+crow0+r_)*VS + ch] = f2bf(1.f/(1.f+__expf(-v)));
                    }
            }
        }
        if (st == 11) {  // v epilogue (no pos, no sigmoid)
            #pragma unroll
            for (int j = 0; j < 2; ++j) {
                const int ch = cw + j*16 + ccol;
                #pragma unroll
                for (int rh = 0; rh < 2; ++rh)
                    #pragma unroll
                    for (int r_ = 0; r_ < 4; ++r_)
                        v_sb[(rh*16+crow0+r_)*VS + ch] =
                            f2bf(vacc[rh][j][r_] + bvv[j]);
            }
        }
    }

    __syncthreads();   // qkv LDS complete

    // ---- attention: 16 threads/location, 32 locations (512 threads) ----
    // Passes 1/2 use BATCHED independent red16s (identical arithmetic and
    // lane-combination order; only instruction-level parallelism changes).
    {
        const int loc = tid >> 4, tt = tid & 15, d0 = tt * 2;
        const int gr = r0 + loc;                 // global row in (n,b) order
        const int nn = gr >> 3, bb = gr & 7;
        const unsigned short* qr = q_sb + loc * VS + d0;
        const unsigned short* kr = k_sb + loc * VS + d0;
        const unsigned short* vr = v_sb + loc * VS + d0;
        f32x2 qh[8], kh[8], vh[8];
        #pragma unroll
        for (int h = 0; h < 8; ++h) {
            const us2 tq = *reinterpret_cast<const us2*>(qr + (h << 5));
            const us2 tk = *reinterpret_cast<const us2*>(kr + (h << 5));
            const us2 tv = *reinterpret_cast<const us2*>(vr + (h << 5));
            qh[h][0] = bf2f(tq[0]); qh[h][1] = bf2f(tq[1]);
            kh[h][0] = bf2f(tk[0]); kh[h][1] = bf2f(tk[1]);
            vh[h][0] = bf2f(tv[0]); vh[h][1] = bf2f(tv[1]);
        }

        // ---- pass 1: p1/p2 partials, then batched reduce
        float pr[8], ps[8];
        {
            f32x2 ck = {0,0}, cq = {0,0};
            #pragma unroll
            for (int h = 0; h < 8; ++h) {
                float p1 = 0.f, p2 = 0.f;
                #pragma unroll
                for (int j = 0; j < 2; ++j) {
                    ck[j] += kh[h][j]; cq[j] += qh[h][j];
                    p1 += (qh[h][j] + EPSV) * (ck[j] + EPSV);
                    p2 += (kh[h][j] + EPSV) * (cq[j] + EPSV);
                }
                pr[h] = p1; ps[h] = p2;
            }
        }
        #pragma unroll
        for (int h = 0; h < 8; ++h) pr[h] = red16(pr[h]);
        #pragma unroll
        for (int h = 0; h < 8; ++h) ps[h] = red16(ps[h]);

        float ir1[8], so_[8];
        #pragma unroll
        for (int h = 0; h < 8; ++h) {
            ir1[h] = 1.f / pr[h];
            so_[h] = (float)(h+1) / ps[h];
        }

        // ---- pass 2: p3/p4 partials, then batched reduce
        float pt[8], pu[8];
        {
            f32x2 c2 = {0,0}, c3 = {0,0};
            #pragma unroll
            for (int h = 0; h < 8; ++h) {
                const float sih = (float)(h+1) * ir1[h];
                float p3 = 0.f, p4 = 0.f;
                #pragma unroll
                for (int j = 0; j < 2; ++j) {
                    c2[j] += kh[h][j] * so_[h];
                    c3[j] += qh[h][j] * sih;
                    p3 += (qh[h][j] + EPSV) * (c2[j] + EPSV);
                    p4 += (kh[h][j] + EPSV) * (c3[j] + EPSV);
                }
                pt[h] = p3; pu[h] = p4;
            }
        }
        #pragma unroll
        for (int h = 0; h < 8; ++h) pt[h] = red16(pt[h]);
        #pragma unroll
        for (int h = 0; h < 8; ++h) pu[h] = red16(pu[h]);

        float salloc[8], scomp[8];
        {
            float css = 0.f;
            #pragma unroll
            for (int h = 0; h < 8; ++h) {
                const float inv_n = 1.f / (float)(h+1);
                salloc[h] = 1.f / (1.f + __expf(-pt[h] * inv_n));
                const float consrc = fminf(1.f, fmaxf(-1.f, pu[h] * inv_n));
                const float cs = __expf(consrc);
                css += cs;
                scomp[h] = cs / css * (float)(h+1);
            }
        }

        // ---- pass 3 (qkv): red16s independent across h2
        #pragma unroll
        for (int h = 0; h < 8; ++h) {
            f32x2 qs2, a2 = {0,0};
            #pragma unroll
            for (int j = 0; j < 2; ++j) qs2[j] = qh[h][j] * ir1[h];
            #pragma unroll
            for (int h2 = 0; h2 <= h; ++h2) {
                float p = 0.f;
                #pragma unroll
                for (int j = 0; j < 2; ++j) p += qs2[j] * kh[h2][j];
                p = red16(p);
                const float w = p * scomp[h2];
                #pragma unroll
                for (int j = 0; j < 2; ++j) a2[j] += w * vh[h2][j];
            }
            us2 o;
            o[0] = f2bf(a2[0] * salloc[h]);
            o[1] = f2bf(a2[1] * salloc[h]);
            *reinterpret_cast<us2*>(abf + (size_t)bb*(H_*N_*D_) + (size_t)h*(N_*D_)
                                        + (size_t)nn*D_ + d0) = o;
        }
    }
}

// ---------------------------------------------------------------------------
// Kernel 2: out-projection + residual. 512 threads = 8 waves x 32 cols,
// wave-private Wo pipeline (4 steps, 2-slice dbuf). A rows are SCRAMBLED
// slices of abf. (r16 proven shape.)
// ---------------------------------------------------------------------------
__global__ __launch_bounds__(512)
void outproj(const unsigned short* __restrict__ abf,
             const unsigned short* __restrict__ wbf,
             const float* __restrict__ bo,
             const float* __restrict__ query,
             float* __restrict__ out)
{
    extern __shared__ char smem[];
    char* Wb = smem;                                     // 8 x (2 x 4 KB)
    unsigned char* As = (unsigned char*)(smem + 65536);  // 16 KB
    const int tid = threadIdx.x;
    const int r0  = blockIdx.x * BM;
    const int wave = tid >> 6, lane = tid & 63;
    const int cw = wave * 32;
    char* mywb = Wb + wave * 8192;
    const unsigned short* Wo = wbf + 3*65536;

    stageW32(Wo, 0, mywb, cw, lane);

    {   // stage scrambled A rows (pure bf16 copy)
        const int trow = tid >> 5, k0 = (tid & 31) * 8;
        #pragma unroll
        for (int i = 0; i < 2; ++i) {
            const int row = trow + i * 16;
            const int gr = r0 + row;
            const int nn = gr >> 3, bb = gr & 7;
            const short8 p = *reinterpret_cast<const short8*>(
                abf + (size_t)bb * (N_*C_) + (size_t)nn * C_ + k0);
            *reinterpret_cast<short8*>(As + swz(row, k0)) = p;
        }
    }

    const int lrow = lane & 15, kg8 = (lane >> 4) * 8;
    const int crow0 = (lane >> 4) * 4, ccol = lane & 15;

    // prefetch bias + residual
    float bov[2], qres[16];
    #pragma unroll
    for (int j = 0; j < 2; ++j) {
        const int ch = cw + j*16 + ccol;
        bov[j] = bo[ch];
        #pragma unroll
        for (int rh = 0; rh < 2; ++rh)
            #pragma unroll
            for (int r_ = 0; r_ < 4; ++r_)
                qres[j*8+rh*4+r_] =
                    query[(size_t)(r0 + rh*16 + crow0 + r_) * C_ + ch];
    }

    __syncthreads();

    f32x4 acc[2][2] = {};
    #pragma unroll
    for (int sp = 0; sp < 4; ++sp) {
        if (sp < 3) {
            stageW32(Wo, (sp+1)*64, mywb + ((sp+1) & 1) * 4096, cw, lane);
            asm volatile("s_waitcnt vmcnt(4)" ::: "memory");
        } else {
            asm volatile("s_waitcnt vmcnt(0)" ::: "memory");
        }
        step_mm32(As, mywb + (sp & 1) * 4096, sp*64, lrow, kg8, acc);
    }

    #pragma unroll
    for (int j = 0; j < 2; ++j) {
        const int ch = cw + j*16 + ccol;
        #pragma unroll
        for (int rh = 0; rh < 2; ++rh)
            #pragma unroll
            for (int r_ = 0; r_ < 4; ++r_) {
                const size_t g = (size_t)(r0 + rh*16 + crow0 + r_) * C_ + ch;
                out[g] = acc[rh][j][r_] + bov[j] + qres[j*8+rh*4+r_];
            }
    }
}

// ---------------------------------------------------------------------------
extern "C" void kernel_launch(void* const* d_in, const int* in_sizes, int n_in,
                              void* d_out, int out_size, void* d_ws, size_t ws_size,
                              hipStream_t stream)
{
    const float* query = (const float*)d_in[0];
    const float* key   = (const float*)d_in[1];
    const float* qpos  = (const float*)d_in[2];
    const float* kpos  = (const float*)d_in[3];
    const float* Wq = (const float*)d_in[4];  const float* bq = (const float*)d_in[5];
    const float* Wk = (const float*)d_in[6];  const float* bk = (const float*)d_in[7];
    const float* Wv = (const float*)d_in[8];  const float* bv = (const float*)d_in[9];
    const float* Wo = (const float*)d_in[10]; const float* bo = (const float*)d_in[11];

    unsigned short* wbf = (unsigned short*)d_ws;        // 4*65536 bf16 = 512 KB
    unsigned short* abf = wbf + 4*65536;                // B*N*C bf16 = 3.7 MB
    float* out = (float*)d_out;

    pack_w<<<128, 256, 0, stream>>>(Wq, Wk, Wv, Wo, wbf);
    fused_qkva<<<NBLK, 512, LDS1, stream>>>(query, key, qpos, kpos, wbf,
                                            bq, bk, bv, abf);
    outproj<<<NBLK, 512, LDS2, stream>>>(abf, wbf, bo, query, out);
}